// Round 8
// baseline (198.270 us; speedup 1.0000x reference)
//
#include <hip/hip_runtime.h>
#include <hip/hip_cooperative_groups.h>
#include <math.h>

namespace cg = cooperative_groups;

#define D 512
#define NC 64
#define NQ 2048

typedef unsigned short u16;
typedef __attribute__((ext_vector_type(8))) short bf8;
typedef __attribute__((ext_vector_type(4))) float f4;

// ---- workspace float offsets ----
#define OFF_S    0
#define OFF_L    32                      // 512x512 fp32 L; REUSED later as YYf (UWp fp32)
#define OFF_W    (OFF_L + D*D)           // 512x512 fp32 W
#define OFF_TMP  (OFF_W + D*D)           // 256x256 doubling temp
#define OFF_ABH  (OFF_TMP + 65536)       // 2560x512 u16 (rows 0-511 Ubp, 512+ Xq) hi
#define OFF_ABL  (OFF_ABH + 655360)      // lo
#define OFF_WH   (OFF_ABL + 655360)      // 512x512 u16 W hi
#define OFF_WL   (OFF_WH + 131072)
#define OFF_YYH  (OFF_WL + 131072)       // 2560x512 u16 YY hi (rows 0-511 UWp, 512+ Y)
#define OFF_YYL  (OFF_YYH + 655360)
#define OFF_AQ   (OFF_YYL + 655360)      // 2048 fp32
#define OFF_MINV (OFF_AQ + NQ)
#define OFF_BIAS (OFF_MINV + NC*36)
#define OFF_H    (OFF_BIAS + NC)
#define OFF_SV   (OFF_H + NC)            // NC*6

__device__ inline float wred(float v) {
#pragma unroll
  for (int off = 32; off; off >>= 1) v += __shfl_down(v, off);
  return v;
}

// split fp32 into hi bf16 (truncated, so v-hi is exact) + lo bf16 (RN)
__device__ inline void split2(float v, u16& h, u16& l) {
  unsigned u = __float_as_uint(v);
  h = (u16)(u >> 16);
  float hf = __uint_as_float(u & 0xFFFF0000u);
  float r = v - hf;
  unsigned ru = __float_as_uint(r);
  l = (u16)((ru + 0x7FFFu + ((ru >> 16) & 1u)) >> 16);
}

// Fused prep: 0..1023 build L (+zero W upper fp32+bf16), 1024..1087 classprep
// (Ubp as bf16 hi/lo), 1088 scalars + aq zero, 1089..1600 Xq->bf16 hi/lo.
__global__ __launch_bounds__(256) void k_prep(const float* __restrict__ diag,
                                              const float* __restrict__ low,
                                              const float* __restrict__ Xs,
                                              const float* __restrict__ Xq,
                                              const float* __restrict__ m,
                                              const float* __restrict__ kp,
                                              const float* __restrict__ nup,
                                              float* __restrict__ L, float* __restrict__ W,
                                              u16* __restrict__ ABh, u16* __restrict__ ABl,
                                              u16* __restrict__ Wh, u16* __restrict__ Wl,
                                              float* __restrict__ S, float* __restrict__ aq) {
  int bid = blockIdx.x, tid = threadIdx.x;
  if (bid < 1024) {
    int t = bid * 256 + tid;
    int i = t >> 9, j = t & 511;
    float v = (i == j) ? fabsf(diag[i]) : (i > j ? low[t] : 0.f);
    L[t] = v;
    if (i < j) { W[t] = 0.f; Wh[t] = 0; Wl[t] = 0; }
  } else if (bid < 1088) {
    int c = bid - 1024;
    float kappa = kp[0];
    float kn = fabsf(kappa) + 1e-6f + 5.0f;
    float xw = 5.0f / kn;
    float mw = fabsf(kappa + 1e-6f) / kn;
    float sw = sqrtf((fabsf(kappa) + 1e-6f) / kn);
    const float is5 = 0.44721359549995793f;
    for (int d = tid; d < D; d += 256) {
      float x[5];
#pragma unroll
      for (int s = 0; s < 5; ++s) x[s] = Xs[(size_t)(c * 5 + s) * D + d];
      float xm = (x[0] + x[1] + x[2] + x[3] + x[4]) * 0.2f;
      float mv = m[d];
      float rowv[8];
#pragma unroll
      for (int s = 0; s < 5; ++s) rowv[s] = x[s] * is5;
      rowv[5] = sw * (xm - mv);
      rowv[6] = mw * mv + xw * xm;
      rowv[7] = 0.f;
#pragma unroll
      for (int s = 0; s < 8; ++s) {
        size_t gi = (size_t)(c * 8 + s) * D + d;
        u16 hh, ll; split2(rowv[s], hh, ll);
        ABh[gi] = hh; ABl[gi] = ll;
      }
    }
  } else if (bid == 1088) {
    for (int i = tid; i < NQ; i += 256) aq[i] = 0.f;
    if (tid >= 64) return;
    float part = 0.f;
    for (int i = tid; i < D; i += 64) part += logf(fabsf(diag[i]));
    part = wred(part);
    if (tid != 0) return;
    float lda = 2.f * part;
    float kappa = kp[0], nu = nup[0];
    float kn = fabsf(kappa) + 1e-6f + 5.0f;
    float sp = fmaxf(nu, (float)(D - 1) + 1e-6f) + 5.0f - (float)D + 2.0f;
    float bias_shared = lgammaf(0.5f * (sp + (float)D)) - lgammaf(0.5f * sp)
                      - 0.5f * (float)D * logf(sp);
    float scale = kn * sp / (kn + 1.0f);
    S[3] = bias_shared;
    S[8] = 1.f / scale;
    S[9] = (float)D * logf(scale) + lda;
    S[10] = 0.5f * (sp + (float)D);
    S[11] = 1.f / sp;
  } else {
    int idx = bid - 1089;                 // 0..511
    size_t base = (size_t)512 * D + (size_t)idx * 2048;
    for (int i = tid; i < 2048; i += 256) {
      float v = Xq[(size_t)idx * 2048 + i];
      u16 hh, ll; split2(v, hh, ll);
      ABh[base + i] = hh; ABl[base + i] = ll;
    }
  }
}

#define MPAD 68

template <int N>
__device__ inline void lds_mm(float (*M)[MPAD], int ar, int ac, int br, int bc,
                              int cr, int cc, bool neg) {
  const int T = N / 16;
  int tx = (threadIdx.x & 15) * T, ty = (threadIdx.x >> 4) * T;
  float acc[T][T];
#pragma unroll
  for (int i = 0; i < T; ++i)
#pragma unroll
    for (int j = 0; j < T; ++j) acc[i][j] = 0.f;
#pragma unroll 8
  for (int k = 0; k < N; ++k) {
    float a[T], b[T];
#pragma unroll
    for (int i = 0; i < T; ++i) a[i] = M[ar + ty + i][ac + k];
#pragma unroll
    for (int j = 0; j < T; ++j) b[j] = M[br + k][bc + tx + j];
#pragma unroll
    for (int i = 0; i < T; ++i)
#pragma unroll
      for (int j = 0; j < T; ++j) acc[i][j] += a[i] * b[j];
  }
#pragma unroll
  for (int i = 0; i < T; ++i)
#pragma unroll
    for (int j = 0; j < T; ++j)
      M[cr + ty + i][cc + tx + j] = neg ? -acc[i][j] : acc[i][j];
}

// 32x32-tile NN GEMM body (one output tile): C = alpha*A@B (+ optional bf16 h/l).
__device__ void nn_tile(const float* __restrict__ Ab, int lda,
                        const float* __restrict__ Bb, int ldb,
                        float* __restrict__ Cb, int ldc,
                        u16* __restrict__ whB, u16* __restrict__ wlB,
                        int n, float alpha, int bm, int bn,
                        float (*As)[33], float (*Bs)[33]) {
  int tid = threadIdx.x;
  int tx = tid & 15, ty = tid >> 4;
  float acc[2][2] = {};
  for (int k0 = 0; k0 < n; k0 += 32) {
    __syncthreads();
    for (int idx = tid; idx < 1024; idx += 256) {
      int r = idx >> 5, c = idx & 31;
      As[r][c] = Ab[(size_t)(bm + r) * lda + k0 + c];
      Bs[r][c] = Bb[(size_t)(k0 + r) * ldb + bn + c];
    }
    __syncthreads();
#pragma unroll
    for (int kk = 0; kk < 32; ++kk) {
      float a0 = As[ty * 2 + 0][kk], a1 = As[ty * 2 + 1][kk];
      float b0 = Bs[kk][tx * 2 + 0], b1 = Bs[kk][tx * 2 + 1];
      acc[0][0] += a0 * b0; acc[0][1] += a0 * b1;
      acc[1][0] += a1 * b0; acc[1][1] += a1 * b1;
    }
  }
#pragma unroll
  for (int i = 0; i < 2; ++i)
#pragma unroll
    for (int j = 0; j < 2; ++j) {
      size_t gi = (size_t)(bm + ty * 2 + i) * ldc + bn + tx * 2 + j;
      float v = alpha * acc[i][j];
      Cb[gi] = v;
      if (whB) { u16 hh, ll; split2(v, hh, ll); whB[gi] = hh; wlB[gi] = ll; }
    }
}

// Cooperative: full W = L^{-1} (fp32 + bf16 h/l) in ONE launch.
// P0: 8 blocks invert 64x64 diag blocks in LDS. Then doubling levels
// n=64,128,256 as grid-role-mapped 32x32-tile GEMM stages with grid syncs.
__global__ __launch_bounds__(256) void k_winv(const float* __restrict__ L,
                                              float* __restrict__ W,
                                              u16* __restrict__ Wh,
                                              u16* __restrict__ Wl,
                                              float* __restrict__ TMP) {
  __shared__ __align__(16) float smem[64 * MPAD];
  cg::grid_group grid = cg::this_grid();
  int bid = blockIdx.x, tid = threadIdx.x;
  if (bid < 8) {
    float (*M)[MPAD] = reinterpret_cast<float(*)[MPAD]>(smem);
    int p = bid * 64;
    for (int idx = tid; idx < 64 * 16; idx += 256) {
      int r = idx >> 4, c4 = (idx & 15) << 2;
      *reinterpret_cast<float4*>(&M[r][c4]) =
          *reinterpret_cast<const float4*>(&L[(size_t)(p + r) * D + p + c4]);
    }
    __syncthreads();
    {
      float x[16];
      int q = tid >> 4, col = tid & 15;
      if (tid < 64) {
        int b = q << 4;
#pragma unroll
        for (int i = 0; i < 16; ++i) {
          float acc = 0.f;
#pragma unroll
          for (int k = 0; k < i; ++k) acc += M[b + i][b + k] * x[k];
          x[i] = (((i == col) ? 1.f : 0.f) - acc) / M[b + i][b + i];
        }
      }
      __syncthreads();
      if (tid < 64) {
        int b = q << 4;
#pragma unroll
        for (int i = 0; i < 16; ++i) M[b + i][b + col] = x[i];
      }
      __syncthreads();
    }
    // level 16 (2 pairs) then level 32 (1 pair), scratch in upper-zero region
    for (int pp = 0; pp < 2; ++pp) {
      int r0 = 32 * pp;
      lds_mm<16>(M, r0 + 16, r0, r0, r0, r0, r0 + 16, false);
    }
    __syncthreads();
    for (int pp = 0; pp < 2; ++pp) {
      int r0 = 32 * pp;
      lds_mm<16>(M, r0 + 16, r0 + 16, r0, r0 + 16, r0 + 16, r0, true);
    }
    __syncthreads();
    lds_mm<32>(M, 32, 0, 0, 0, 0, 32, false);
    __syncthreads();
    lds_mm<32>(M, 32, 32, 0, 32, 32, 0, true);
    __syncthreads();
    for (int idx = tid; idx < 64 * 16; idx += 256) {
      int r = idx >> 4, c4 = (idx & 15) << 2;
      float4 v = *reinterpret_cast<const float4*>(&M[r][c4]);
      if (c4 + 0 > r) v.x = 0.f;
      if (c4 + 1 > r) v.y = 0.f;
      if (c4 + 2 > r) v.z = 0.f;
      if (c4 + 3 > r) v.w = 0.f;
      size_t gi = (size_t)(p + r) * D + p + c4;
      *reinterpret_cast<float4*>(&W[gi]) = v;
      float vv[4] = {v.x, v.y, v.z, v.w};
#pragma unroll
      for (int e = 0; e < 4; ++e) {
        u16 hh, ll; split2(vv[e], hh, ll);
        Wh[gi + e] = hh; Wl[gi + e] = ll;
      }
    }
  }
  grid.sync();
  float (*As)[33] = reinterpret_cast<float(*)[33]>(smem);
  float (*Bs)[33] = reinterpret_cast<float(*)[33]>(smem + 32 * 33);
  for (int lev = 0; lev < 3; ++lev) {
    int n = 64 << lev, g = n >> 5, npair = 4 >> lev, bpp = g * g;
    if (bid < npair * bpp) {
      int z = bid / bpp, rem = bid % bpp, by = rem / g, bx = rem % g;
      int r0 = 2 * n * z;
      nn_tile(L + (size_t)(r0 + n) * D + r0, D,
              W + (size_t)r0 * D + r0, D,
              TMP + (size_t)z * n * n, n, (u16*)nullptr, (u16*)nullptr,
              n, 1.f, by * 32, bx * 32, As, Bs);
    }
    grid.sync();
    if (bid < npair * bpp) {
      int z = bid / bpp, rem = bid % bpp, by = rem / g, bx = rem % g;
      int r0 = 2 * n * z;
      size_t off = (size_t)(r0 + n) * D + r0;
      nn_tile(W + (size_t)(r0 + n) * D + (r0 + n), D,
              TMP + (size_t)z * n * n, n,
              W + off, D, Wh + off, Wl + off,
              n, -1.f, by * 32, bx * 32, As, Bs);
    }
    if (lev < 2) grid.sync();
  }
}

// GEMM1 (MFMA split-bf16): YY = [Ubp;Xq] @ W^T, tri-clipped. Fused: fp32 YYf
// write (rows<512), bf16 h/l YY write (all rows), aq += rowsumsq (rows>=512).
__global__ __launch_bounds__(256) void k_mf1(const u16* __restrict__ ABh, const u16* __restrict__ ABl,
                                             const u16* __restrict__ Wh, const u16* __restrict__ Wl,
                                             u16* __restrict__ YYh, u16* __restrict__ YYl,
                                             float* __restrict__ YYf, float* __restrict__ aq) {
  int tid = threadIdx.x, w = tid >> 6, lane = tid & 63;
  int m0 = blockIdx.x * 64 + w * 16;
  int bn = blockIdx.y * 64;
  int lr = lane & 15, kof = (lane >> 4) * 8;
  const u16* ah_p = ABh + (size_t)(m0 + lr) * D + kof;
  const u16* al_p = ABl + (size_t)(m0 + lr) * D + kof;
  const u16* bh_p = Wh + (size_t)(bn + lr) * D + kof;
  const u16* bl_p = Wl + (size_t)(bn + lr) * D + kof;
  f4 acc[4];
#pragma unroll
  for (int nf = 0; nf < 4; ++nf) acc[nf] = (f4){0.f, 0.f, 0.f, 0.f};
  int Klim = bn + 64;
#pragma unroll 2
  for (int k0 = 0; k0 < Klim; k0 += 32) {
    bf8 ah = *reinterpret_cast<const bf8*>(ah_p + k0);
    bf8 al = *reinterpret_cast<const bf8*>(al_p + k0);
    bf8 bh[4], bl[4];
#pragma unroll
    for (int nf = 0; nf < 4; ++nf) {
      bh[nf] = *reinterpret_cast<const bf8*>(bh_p + (size_t)nf * 16 * D + k0);
      bl[nf] = *reinterpret_cast<const bf8*>(bl_p + (size_t)nf * 16 * D + k0);
    }
#pragma unroll
    for (int nf = 0; nf < 4; ++nf)
      acc[nf] = __builtin_amdgcn_mfma_f32_16x16x32_bf16(ah, bh[nf], acc[nf], 0, 0, 0);
#pragma unroll
    for (int nf = 0; nf < 4; ++nf)
      acc[nf] = __builtin_amdgcn_mfma_f32_16x16x32_bf16(ah, bl[nf], acc[nf], 0, 0, 0);
#pragma unroll
    for (int nf = 0; nf < 4; ++nf)
      acc[nf] = __builtin_amdgcn_mfma_f32_16x16x32_bf16(al, bh[nf], acc[nf], 0, 0, 0);
  }
  int rbase = m0 + ((lane >> 4) << 2);   // C layout: row=(lane>>4)*4+reg, col=lane&15
#pragma unroll
  for (int reg = 0; reg < 4; ++reg) {
    int row = rbase + reg;
    float sq = 0.f;
#pragma unroll
    for (int nf = 0; nf < 4; ++nf) {
      float v = acc[nf][reg];
      size_t gi = (size_t)row * D + bn + nf * 16 + lr;
      u16 hh, ll; split2(v, hh, ll);
      YYh[gi] = hh; YYl[gi] = ll;
      if (row < 512) YYf[gi] = v;
      sq += v * v;
    }
    if (row >= 512) {
#pragma unroll
      for (int mk = 1; mk < 16; mk <<= 1) sq += __shfl_xor(sq, mk);
      if (lr == 0) atomicAdd(&aq[row - 512], sq);
    }
  }
}

// GEMM2 (MFMA split-bf16) + fused MetaQDA epilogue: out = epi(Y @ UWp^T).
__global__ __launch_bounds__(256) void k_mf2(const u16* __restrict__ Yh, const u16* __restrict__ Yl,
                                             const u16* __restrict__ Bh, const u16* __restrict__ Bl,
                                             const float* __restrict__ aq, const float* __restrict__ sv,
                                             const float* __restrict__ Minv, const float* __restrict__ biasv,
                                             const float* __restrict__ hb, const float* __restrict__ S,
                                             float* __restrict__ out) {
  __shared__ float Csh[4][16][68];
  int tid = threadIdx.x, w = tid >> 6, lane = tid & 63;
  int bm = blockIdx.x * 64, m0 = bm + w * 16;
  int bn = blockIdx.y * 64;
  int lr = lane & 15, kof = (lane >> 4) * 8;
  const u16* ah_p = Yh + (size_t)(m0 + lr) * D + kof;
  const u16* al_p = Yl + (size_t)(m0 + lr) * D + kof;
  const u16* bh_p = Bh + (size_t)(bn + lr) * D + kof;
  const u16* bl_p = Bl + (size_t)(bn + lr) * D + kof;
  f4 acc[4];
#pragma unroll
  for (int nf = 0; nf < 4; ++nf) acc[nf] = (f4){0.f, 0.f, 0.f, 0.f};
#pragma unroll 2
  for (int k0 = 0; k0 < D; k0 += 32) {
    bf8 ah = *reinterpret_cast<const bf8*>(ah_p + k0);
    bf8 al = *reinterpret_cast<const bf8*>(al_p + k0);
    bf8 bh[4], bl[4];
#pragma unroll
    for (int nf = 0; nf < 4; ++nf) {
      bh[nf] = *reinterpret_cast<const bf8*>(bh_p + (size_t)nf * 16 * D + k0);
      bl[nf] = *reinterpret_cast<const bf8*>(bl_p + (size_t)nf * 16 * D + k0);
    }
#pragma unroll
    for (int nf = 0; nf < 4; ++nf)
      acc[nf] = __builtin_amdgcn_mfma_f32_16x16x32_bf16(ah, bh[nf], acc[nf], 0, 0, 0);
#pragma unroll
    for (int nf = 0; nf < 4; ++nf)
      acc[nf] = __builtin_amdgcn_mfma_f32_16x16x32_bf16(ah, bl[nf], acc[nf], 0, 0, 0);
#pragma unroll
    for (int nf = 0; nf < 4; ++nf)
      acc[nf] = __builtin_amdgcn_mfma_f32_16x16x32_bf16(al, bh[nf], acc[nf], 0, 0, 0);
  }
#pragma unroll
  for (int reg = 0; reg < 4; ++reg)
#pragma unroll
    for (int nf = 0; nf < 4; ++nf)
      Csh[w][((lane >> 4) << 2) + reg][nf * 16 + lr] = acc[nf][reg];
  __syncthreads();
  float s8 = S[8], s10 = S[10], s11 = S[11];
  int r = lr;
  int q = m0 + r;
  float aqv = aq[q];
#pragma unroll
  for (int cc = 0; cc < 2; ++cc) {
    int cl = ((lane >> 4) << 1) + cc;
    int c = blockIdx.y * 8 + cl;
    const float* t = &Csh[w][r][cl * 8];
    float e[6];
#pragma unroll
    for (int j = 0; j < 6; ++j) e[j] = t[j] - sv[c * 6 + j];
    float quad = 0.f;
#pragma unroll
    for (int i = 0; i < 6; ++i) {
      float a = 0.f;
#pragma unroll
      for (int j = 0; j < 6; ++j) a += Minv[c * 36 + i * 6 + j] * e[j];
      quad += e[i] * a;
    }
    float dist = (aqv - 2.f * t[6] + hb[c] - quad) * s8;
    out[(size_t)q * NC + c] = biasv[c] - s10 * log1pf(dist * s11);
  }
}

// per class: 7x7 Gram of fp32 UWp rows -> Minv, logdet, bias, sv, h.
__global__ __launch_bounds__(256) void k_msmall(const float* __restrict__ YYf,
                                                const float* __restrict__ S,
                                                float* __restrict__ Minv, float* __restrict__ biasv,
                                                float* __restrict__ hbuf, float* __restrict__ svec) {
  __shared__ float4 R4[7 * 128];
  __shared__ float Dsh[49];
  int c = blockIdx.x, tid = threadIdx.x;
  int lane = tid & 63, wave = tid >> 6;
  const float4* src = reinterpret_cast<const float4*>(YYf + (size_t)c * 8 * D);
  for (int idx = tid; idx < 7 * 128; idx += 256) R4[idx] = src[idx];
  __syncthreads();
  const float* R = reinterpret_cast<const float*>(R4);
  const int PI[28] = {0,0,0,0,0,0,0, 1,1,1,1,1,1, 2,2,2,2,2, 3,3,3,3, 4,4,4, 5,5, 6};
  const int PJ[28] = {0,1,2,3,4,5,6, 1,2,3,4,5,6, 2,3,4,5,6, 3,4,5,6, 4,5,6, 5,6, 6};
  for (int p = wave; p < 28; p += 4) {
    int i = PI[p], j = PJ[p];
    float part = 0.f;
#pragma unroll
    for (int it = 0; it < 8; ++it) {
      int d = lane + it * 64;
      part += R[i * D + d] * R[j * D + d];
    }
    part = wred(part);
    if (lane == 0) { Dsh[i * 7 + j] = part; Dsh[j * 7 + i] = part; }
  }
  __syncthreads();
  if (tid == 0) {
    float Mm[6][6], Rc[6][6], Rin[6][6];
    for (int i = 0; i < 6; ++i)
      for (int j = 0; j < 6; ++j) {
        Mm[i][j] = Dsh[i * 7 + j] + (i == j ? 1.f : 0.f);
        Rc[i][j] = 0.f; Rin[i][j] = 0.f;
      }
    float logdetM = 0.f;
    for (int i = 0; i < 6; ++i) {
      float s = Mm[i][i];
      for (int k = 0; k < i; ++k) s -= Rc[i][k] * Rc[i][k];
      float rii = sqrtf(s);
      Rc[i][i] = rii;
      logdetM += logf(rii);
      for (int r = i + 1; r < 6; ++r) {
        float s2 = Mm[r][i];
        for (int k = 0; k < i; ++k) s2 -= Rc[r][k] * Rc[i][k];
        Rc[r][i] = s2 / rii;
      }
    }
    logdetM *= 2.f;
    for (int j = 0; j < 6; ++j) {
      Rin[j][j] = 1.f / Rc[j][j];
      for (int i = j + 1; i < 6; ++i) {
        float s3 = 0.f;
        for (int k = j; k < i; ++k) s3 += Rc[i][k] * Rin[k][j];
        Rin[i][j] = -s3 / Rc[i][i];
      }
    }
    for (int i = 0; i < 6; ++i)
      for (int j = 0; j < 6; ++j) {
        float s4 = 0.f;
        for (int k = 0; k < 6; ++k) s4 += Rin[k][i] * Rin[k][j];
        Minv[c * 36 + i * 6 + j] = s4;
      }
    for (int j = 0; j < 6; ++j) svec[c * 6 + j] = Dsh[j * 7 + 6];
    hbuf[c] = Dsh[48];
    biasv[c] = S[3] - 0.5f * (S[9] + logdetM);
  }
}

extern "C" void kernel_launch(void* const* d_in, const int* in_sizes, int n_in,
                              void* d_out, int out_size, void* d_ws, size_t ws_size,
                              hipStream_t stream) {
  const float* Xs   = (const float*)d_in[0];
  const float* Xq   = (const float*)d_in[2];
  const float* m    = (const float*)d_in[3];
  const float* kap  = (const float*)d_in[4];
  const float* nu   = (const float*)d_in[5];
  const float* diag = (const float*)d_in[6];
  const float* low  = (const float*)d_in[7];
  float* ws = (float*)d_ws;

  float* S    = ws + OFF_S;
  float* L    = ws + OFF_L;
  float* YYf  = ws + OFF_L;      // aliases L: all L reads finish before k_mf1
  float* W    = ws + OFF_W;
  float* TMP  = ws + OFF_TMP;
  u16*   ABh  = (u16*)(ws + OFF_ABH);
  u16*   ABl  = (u16*)(ws + OFF_ABL);
  u16*   Wh   = (u16*)(ws + OFF_WH);
  u16*   Wl   = (u16*)(ws + OFF_WL);
  u16*   YYh  = (u16*)(ws + OFF_YYH);
  u16*   YYl  = (u16*)(ws + OFF_YYL);
  float* aq   = ws + OFF_AQ;
  float* Minv = ws + OFF_MINV;
  float* bias = ws + OFF_BIAS;
  float* hb   = ws + OFF_H;
  float* sv   = ws + OFF_SV;

  hipLaunchKernelGGL(k_prep, dim3(1601), dim3(256), 0, stream,
                     diag, low, Xs, Xq, m, kap, nu, L, W, ABh, ABl, Wh, Wl, S, aq);
  {
    void* args[] = {(void*)&L, (void*)&W, (void*)&Wh, (void*)&Wl, (void*)&TMP};
    hipLaunchCooperativeKernel((const void*)k_winv, dim3(64), dim3(256), args, 0, stream);
  }
  // GEMM1: YY = [Ubp;Xq] @ W^T (2560x512x512 tri-clipped) + aq atomics
  hipLaunchKernelGGL(k_mf1, dim3(40, 8), dim3(256), 0, stream,
                     ABh, ABl, Wh, Wl, YYh, YYl, YYf, aq);
  hipLaunchKernelGGL(k_msmall, dim3(NC), dim3(256), 0, stream, YYf, S, Minv, bias, hb, sv);
  // GEMM2: out = epilogue(Y @ UWp^T) (2048x512x512)
  hipLaunchKernelGGL(k_mf2, dim3(32, 8), dim3(256), 0, stream,
                     YYh + (size_t)512 * D, YYl + (size_t)512 * D, YYh, YYl,
                     aq, sv, Minv, bias, hb, S, (float*)d_out);
}

// Round 9
// 106.273 us; speedup vs baseline: 1.8657x; 1.8657x over previous
//
#include <hip/hip_runtime.h>
#include <math.h>

#define D 512
#define NC 64
#define NQ 2048

typedef unsigned short u16;
typedef __attribute__((ext_vector_type(8))) short bf8;
typedef __attribute__((ext_vector_type(4))) float f4;

// ---- workspace float offsets ----
#define OFF_S    0
#define OFF_ABH  32                       // 2560x512 u16 (rows 0-511 Ubp, 512+ Xq) hi
#define OFF_ABL  (OFF_ABH + 655360)
#define OFF_LH   (OFF_ABL + 655360)       // 512x512 u16 L hi/lo
#define OFF_LL   (OFF_LH + 131072)
#define OFF_WH   (OFF_LL + 131072)        // 512x512 u16 W hi/lo
#define OFF_WL   (OFF_WH + 131072)
#define OFF_YYH  (OFF_WL + 131072)        // 2560x512 u16 YY hi/lo
#define OFF_YYL  (OFF_YYH + 655360)
#define OFF_YYF  (OFF_YYL + 655360)       // 512x512 fp32 UWp
#define OFF_AQ   (OFF_YYF + 262144)
#define OFF_MINV (OFF_AQ + NQ)
#define OFF_BIAS (OFF_MINV + NC*36)
#define OFF_H    (OFF_BIAS + NC)
#define OFF_SV   (OFF_H + NC)
// total ~ 3.41M floats ~ 13.7 MB

__device__ inline float wred(float v) {
#pragma unroll
  for (int off = 32; off; off >>= 1) v += __shfl_down(v, off);
  return v;
}

// split fp32 into hi bf16 (truncated, so v-hi is exact) + lo bf16 (RN)
__device__ inline void split2(float v, u16& h, u16& l) {
  unsigned u = __float_as_uint(v);
  h = (u16)(u >> 16);
  float hf = __uint_as_float(u & 0xFFFF0000u);
  float r = v - hf;
  unsigned ru = __float_as_uint(r);
  l = (u16)((ru + 0x7FFFu + ((ru >> 16) & 1u)) >> 16);
}

#define MPAD 68
template <int N>
__device__ inline void lds_mm(float (*M)[MPAD], int ar, int ac, int br, int bc,
                              int cr, int cc, bool neg) {
  const int T = N / 16;
  int tx = (threadIdx.x & 15) * T, ty = (threadIdx.x >> 4) * T;
  float acc[T][T];
#pragma unroll
  for (int i = 0; i < T; ++i)
#pragma unroll
    for (int j = 0; j < T; ++j) acc[i][j] = 0.f;
#pragma unroll 8
  for (int k = 0; k < N; ++k) {
    float a[T], b[T];
#pragma unroll
    for (int i = 0; i < T; ++i) a[i] = M[ar + ty + i][ac + k];
#pragma unroll
    for (int j = 0; j < T; ++j) b[j] = M[br + k][bc + tx + j];
#pragma unroll
    for (int i = 0; i < T; ++i)
#pragma unroll
      for (int j = 0; j < T; ++j) acc[i][j] += a[i] * b[j];
  }
#pragma unroll
  for (int i = 0; i < T; ++i)
#pragma unroll
    for (int j = 0; j < T; ++j)
      M[cr + ty + i][cc + tx + j] = neg ? -acc[i][j] : acc[i][j];
}

// Fused prep (1609 blocks):
//   0..1023   : L -> Lh/Ll split; zero W upper (h/l)
//   1024..1087: classprep -> ABh/ABl rows c*8..
//   1088      : scalars + aq zero
//   1089..1600: Xq -> ABh/ABl rows 512..
//   1601..1608: invert 64x64 diag block of L in LDS -> W diag (h/l)
__global__ __launch_bounds__(256) void k_prep(const float* __restrict__ diag,
                                              const float* __restrict__ low,
                                              const float* __restrict__ Xs,
                                              const float* __restrict__ Xq,
                                              const float* __restrict__ m,
                                              const float* __restrict__ kp,
                                              const float* __restrict__ nup,
                                              u16* __restrict__ Lh, u16* __restrict__ Ll,
                                              u16* __restrict__ ABh, u16* __restrict__ ABl,
                                              u16* __restrict__ Wh, u16* __restrict__ Wl,
                                              float* __restrict__ S, float* __restrict__ aq) {
  __shared__ float M[64][MPAD];
  int bid = blockIdx.x, tid = threadIdx.x;
  if (bid < 1024) {
    int t = bid * 256 + tid;
    int i = t >> 9, j = t & 511;
    float v = (i == j) ? fabsf(diag[i]) : (i > j ? low[t] : 0.f);
    u16 hh, ll; split2(v, hh, ll);
    Lh[t] = hh; Ll[t] = ll;
    if (i < j) { Wh[t] = 0; Wl[t] = 0; }
  } else if (bid < 1088) {
    int c = bid - 1024;
    float kappa = kp[0];
    float kn = fabsf(kappa) + 1e-6f + 5.0f;
    float xw = 5.0f / kn;
    float mw = fabsf(kappa + 1e-6f) / kn;
    float sw = sqrtf((fabsf(kappa) + 1e-6f) / kn);
    const float is5 = 0.44721359549995793f;
    for (int d = tid; d < D; d += 256) {
      float x[5];
#pragma unroll
      for (int s = 0; s < 5; ++s) x[s] = Xs[(size_t)(c * 5 + s) * D + d];
      float xm = (x[0] + x[1] + x[2] + x[3] + x[4]) * 0.2f;
      float mv = m[d];
      float rowv[8];
#pragma unroll
      for (int s = 0; s < 5; ++s) rowv[s] = x[s] * is5;
      rowv[5] = sw * (xm - mv);
      rowv[6] = mw * mv + xw * xm;
      rowv[7] = 0.f;
#pragma unroll
      for (int s = 0; s < 8; ++s) {
        size_t gi = (size_t)(c * 8 + s) * D + d;
        u16 hh, ll; split2(rowv[s], hh, ll);
        ABh[gi] = hh; ABl[gi] = ll;
      }
    }
  } else if (bid == 1088) {
    for (int i = tid; i < NQ; i += 256) aq[i] = 0.f;
    if (tid >= 64) return;
    float part = 0.f;
    for (int i = tid; i < D; i += 64) part += logf(fabsf(diag[i]));
    part = wred(part);
    if (tid != 0) return;
    float lda = 2.f * part;
    float kappa = kp[0], nu = nup[0];
    float kn = fabsf(kappa) + 1e-6f + 5.0f;
    float sp = fmaxf(nu, (float)(D - 1) + 1e-6f) + 5.0f - (float)D + 2.0f;
    float bias_shared = lgammaf(0.5f * (sp + (float)D)) - lgammaf(0.5f * sp)
                      - 0.5f * (float)D * logf(sp);
    float scale = kn * sp / (kn + 1.0f);
    S[3] = bias_shared;
    S[8] = 1.f / scale;
    S[9] = (float)D * logf(scale) + lda;
    S[10] = 0.5f * (sp + (float)D);
    S[11] = 1.f / sp;
  } else if (bid < 1601) {
    int idx = bid - 1089;
    size_t base = (size_t)512 * D + (size_t)idx * 2048;
    for (int i = tid; i < 2048; i += 256) {
      float v = Xq[(size_t)idx * 2048 + i];
      u16 hh, ll; split2(v, hh, ll);
      ABh[base + i] = hh; ABl[base + i] = ll;
    }
  } else {
    // invert diag block (64x64) built directly from inputs
    int p = (bid - 1601) * 64;
    for (int idx = tid; idx < 64 * 64; idx += 256) {
      int r = idx >> 6, c = idx & 63;
      float v;
      if (r == c)      v = fabsf(diag[p + r]);
      else if (r > c)  v = low[(size_t)(p + r) * D + p + c];
      else             v = 0.f;
      M[r][c] = v;
    }
    __syncthreads();
    {
      float x[16];
      int q = tid >> 4, col = tid & 15;
      if (tid < 64) {
        int b = q << 4;
#pragma unroll
        for (int i = 0; i < 16; ++i) {
          float acc = 0.f;
#pragma unroll
          for (int k = 0; k < i; ++k) acc += M[b + i][b + k] * x[k];
          x[i] = (((i == col) ? 1.f : 0.f) - acc) / M[b + i][b + i];
        }
      }
      __syncthreads();
      if (tid < 64) {
        int b = q << 4;
#pragma unroll
        for (int i = 0; i < 16; ++i) M[b + i][b + col] = x[i];
      }
      __syncthreads();
    }
    // level 16 (2 pairs), then level 32 (1 pair); scratch in upper-zero region
    for (int pp = 0; pp < 2; ++pp) {
      int r0 = 32 * pp;
      lds_mm<16>(M, r0 + 16, r0, r0, r0, r0, r0 + 16, false);
    }
    __syncthreads();
    for (int pp = 0; pp < 2; ++pp) {
      int r0 = 32 * pp;
      lds_mm<16>(M, r0 + 16, r0 + 16, r0, r0 + 16, r0 + 16, r0, true);
    }
    __syncthreads();
    lds_mm<32>(M, 32, 0, 0, 0, 0, 32, false);
    __syncthreads();
    lds_mm<32>(M, 32, 32, 0, 32, 32, 0, true);
    __syncthreads();
    for (int idx = tid; idx < 64 * 64; idx += 256) {
      int r = idx >> 6, c = idx & 63;
      float v = (c > r) ? 0.f : M[r][c];
      u16 hh, ll; split2(v, hh, ll);
      size_t gi = (size_t)(p + r) * D + p + c;
      Wh[gi] = hh; Wl[gi] = ll;
    }
  }
}

// One-kernel W = L^{-1} column-panel solve (MFMA split-bf16, no cross-block deps).
// Block J owns W cols [32J, 32J+32). Forward substitution over 64-row blocks:
//   X_i = -Dinv_i @ (sum_{k=i0}^{i-1} L_ik X_k),  X_{i0} = Dinv_{i0} col-slice.
// Panel kept transposed (XT) in LDS as bf16 h/l; Dinv blocks read from W diag.
__global__ __launch_bounds__(256) void k_solve(const u16* __restrict__ Lh,
                                               const u16* __restrict__ Ll,
                                               u16* __restrict__ Wh,
                                               u16* __restrict__ Wl) {
  __shared__ __align__(16) u16 XTh[32][520];
  __shared__ __align__(16) u16 XTl[32][520];
  __shared__ __align__(16) u16 STh[32][72];
  __shared__ __align__(16) u16 STl[32][72];
  int J = blockIdx.x;
  int i0 = J >> 1;
  int tid = threadIdx.x, w = tid >> 6, lane = tid & 63;
  int lr = lane & 15, kq = lane >> 4;
  // seed: XT[c][64*i0+r] = Dinv_{i0}[r][(J&1)*32 + c]
  for (int idx = tid; idx < 64 * 32; idx += 256) {
    int r = idx >> 5, c = idx & 31;
    size_t gi = (size_t)(64 * i0 + r) * D + 64 * i0 + (J & 1) * 32 + c;
    XTh[c][64 * i0 + r] = Wh[gi];
    XTl[c][64 * i0 + r] = Wl[gi];
  }
  __syncthreads();
  for (int i = i0 + 1; i < 8; ++i) {
    // GEMM1: S = sum_k L_ik X_k ; wave w -> rows w*16..+16, n-frags 0..1
    f4 acc[2];
    acc[0] = (f4){0.f, 0.f, 0.f, 0.f};
    acc[1] = (f4){0.f, 0.f, 0.f, 0.f};
    for (int k = i0; k < i; ++k) {
#pragma unroll
      for (int kk = 0; kk < 2; ++kk) {
        size_t ga = (size_t)(64 * i + w * 16 + lr) * D + 64 * k + kk * 32 + kq * 8;
        bf8 ah = *reinterpret_cast<const bf8*>(Lh + ga);
        bf8 al = *reinterpret_cast<const bf8*>(Ll + ga);
#pragma unroll
        for (int nf = 0; nf < 2; ++nf) {
          bf8 bh = *reinterpret_cast<const bf8*>(&XTh[nf * 16 + lr][64 * k + kk * 32 + kq * 8]);
          bf8 bl = *reinterpret_cast<const bf8*>(&XTl[nf * 16 + lr][64 * k + kk * 32 + kq * 8]);
          acc[nf] = __builtin_amdgcn_mfma_f32_16x16x32_bf16(ah, bh, acc[nf], 0, 0, 0);
          acc[nf] = __builtin_amdgcn_mfma_f32_16x16x32_bf16(ah, bl, acc[nf], 0, 0, 0);
          acc[nf] = __builtin_amdgcn_mfma_f32_16x16x32_bf16(al, bh, acc[nf], 0, 0, 0);
        }
      }
    }
    // ST = -S^T (h/l)
#pragma unroll
    for (int nf = 0; nf < 2; ++nf)
#pragma unroll
      for (int reg = 0; reg < 4; ++reg) {
        float v = -acc[nf][reg];
        u16 hh, ll; split2(v, hh, ll);
        int c = nf * 16 + lr, r = w * 16 + kq * 4 + reg;
        STh[c][r] = hh; STl[c][r] = ll;
      }
    __syncthreads();
    // GEMM2: X_i = NT(Dinv_i, ST)
    f4 acc2[2];
    acc2[0] = (f4){0.f, 0.f, 0.f, 0.f};
    acc2[1] = (f4){0.f, 0.f, 0.f, 0.f};
#pragma unroll
    for (int kk = 0; kk < 2; ++kk) {
      size_t ga = (size_t)(64 * i + w * 16 + lr) * D + 64 * i + kk * 32 + kq * 8;
      bf8 ah = *reinterpret_cast<const bf8*>(Wh + ga);
      bf8 al = *reinterpret_cast<const bf8*>(Wl + ga);
#pragma unroll
      for (int nf = 0; nf < 2; ++nf) {
        bf8 bh = *reinterpret_cast<const bf8*>(&STh[nf * 16 + lr][kk * 32 + kq * 8]);
        bf8 bl = *reinterpret_cast<const bf8*>(&STl[nf * 16 + lr][kk * 32 + kq * 8]);
        acc2[nf] = __builtin_amdgcn_mfma_f32_16x16x32_bf16(ah, bh, acc2[nf], 0, 0, 0);
        acc2[nf] = __builtin_amdgcn_mfma_f32_16x16x32_bf16(ah, bl, acc2[nf], 0, 0, 0);
        acc2[nf] = __builtin_amdgcn_mfma_f32_16x16x32_bf16(al, bh, acc2[nf], 0, 0, 0);
      }
    }
    // write X_i to global W (h/l) and XT
#pragma unroll
    for (int nf = 0; nf < 2; ++nf)
#pragma unroll
      for (int reg = 0; reg < 4; ++reg) {
        float v = acc2[nf][reg];
        u16 hh, ll; split2(v, hh, ll);
        int r = w * 16 + kq * 4 + reg, c = nf * 16 + lr;
        size_t gi = (size_t)(64 * i + r) * D + 32 * J + c;
        Wh[gi] = hh; Wl[gi] = ll;
        XTh[c][64 * i + r] = hh; XTl[c][64 * i + r] = ll;
      }
    __syncthreads();
  }
}

// GEMM1 (MFMA split-bf16): YY = [Ubp;Xq] @ W^T, tri-clipped. Fused: fp32 YYf
// (rows<512), bf16 h/l YY (all rows), aq += rowsumsq (rows>=512).
__global__ __launch_bounds__(256) void k_mf1(const u16* __restrict__ ABh, const u16* __restrict__ ABl,
                                             const u16* __restrict__ Wh, const u16* __restrict__ Wl,
                                             u16* __restrict__ YYh, u16* __restrict__ YYl,
                                             float* __restrict__ YYf, float* __restrict__ aq) {
  int tid = threadIdx.x, w = tid >> 6, lane = tid & 63;
  int m0 = blockIdx.x * 64 + w * 16;
  int bn = blockIdx.y * 64;
  int lr = lane & 15, kof = (lane >> 4) * 8;
  const u16* ah_p = ABh + (size_t)(m0 + lr) * D + kof;
  const u16* al_p = ABl + (size_t)(m0 + lr) * D + kof;
  const u16* bh_p = Wh + (size_t)(bn + lr) * D + kof;
  const u16* bl_p = Wl + (size_t)(bn + lr) * D + kof;
  f4 acc[4];
#pragma unroll
  for (int nf = 0; nf < 4; ++nf) acc[nf] = (f4){0.f, 0.f, 0.f, 0.f};
  int Klim = bn + 64;
#pragma unroll 2
  for (int k0 = 0; k0 < Klim; k0 += 32) {
    bf8 ah = *reinterpret_cast<const bf8*>(ah_p + k0);
    bf8 al = *reinterpret_cast<const bf8*>(al_p + k0);
    bf8 bh[4], bl[4];
#pragma unroll
    for (int nf = 0; nf < 4; ++nf) {
      bh[nf] = *reinterpret_cast<const bf8*>(bh_p + (size_t)nf * 16 * D + k0);
      bl[nf] = *reinterpret_cast<const bf8*>(bl_p + (size_t)nf * 16 * D + k0);
    }
#pragma unroll
    for (int nf = 0; nf < 4; ++nf)
      acc[nf] = __builtin_amdgcn_mfma_f32_16x16x32_bf16(ah, bh[nf], acc[nf], 0, 0, 0);
#pragma unroll
    for (int nf = 0; nf < 4; ++nf)
      acc[nf] = __builtin_amdgcn_mfma_f32_16x16x32_bf16(ah, bl[nf], acc[nf], 0, 0, 0);
#pragma unroll
    for (int nf = 0; nf < 4; ++nf)
      acc[nf] = __builtin_amdgcn_mfma_f32_16x16x32_bf16(al, bh[nf], acc[nf], 0, 0, 0);
  }
  int rbase = m0 + ((lane >> 4) << 2);
#pragma unroll
  for (int reg = 0; reg < 4; ++reg) {
    int row = rbase + reg;
    float sq = 0.f;
#pragma unroll
    for (int nf = 0; nf < 4; ++nf) {
      float v = acc[nf][reg];
      size_t gi = (size_t)row * D + bn + nf * 16 + lr;
      u16 hh, ll; split2(v, hh, ll);
      YYh[gi] = hh; YYl[gi] = ll;
      if (row < 512) YYf[gi] = v;
      sq += v * v;
    }
    if (row >= 512) {
#pragma unroll
      for (int mk = 1; mk < 16; mk <<= 1) sq += __shfl_xor(sq, mk);
      if (lr == 0) atomicAdd(&aq[row - 512], sq);
    }
  }
}

// GEMM2 (MFMA split-bf16) + fused MetaQDA epilogue: out = epi(Y @ UWp^T).
__global__ __launch_bounds__(256) void k_mf2(const u16* __restrict__ Yh, const u16* __restrict__ Yl,
                                             const u16* __restrict__ Bh, const u16* __restrict__ Bl,
                                             const float* __restrict__ aq, const float* __restrict__ sv,
                                             const float* __restrict__ Minv, const float* __restrict__ biasv,
                                             const float* __restrict__ hb, const float* __restrict__ S,
                                             float* __restrict__ out) {
  __shared__ float Csh[4][16][68];
  int tid = threadIdx.x, w = tid >> 6, lane = tid & 63;
  int bm = blockIdx.x * 64, m0 = bm + w * 16;
  int bn = blockIdx.y * 64;
  int lr = lane & 15, kof = (lane >> 4) * 8;
  const u16* ah_p = Yh + (size_t)(m0 + lr) * D + kof;
  const u16* al_p = Yl + (size_t)(m0 + lr) * D + kof;
  const u16* bh_p = Bh + (size_t)(bn + lr) * D + kof;
  const u16* bl_p = Bl + (size_t)(bn + lr) * D + kof;
  f4 acc[4];
#pragma unroll
  for (int nf = 0; nf < 4; ++nf) acc[nf] = (f4){0.f, 0.f, 0.f, 0.f};
#pragma unroll 2
  for (int k0 = 0; k0 < D; k0 += 32) {
    bf8 ah = *reinterpret_cast<const bf8*>(ah_p + k0);
    bf8 al = *reinterpret_cast<const bf8*>(al_p + k0);
    bf8 bh[4], bl[4];
#pragma unroll
    for (int nf = 0; nf < 4; ++nf) {
      bh[nf] = *reinterpret_cast<const bf8*>(bh_p + (size_t)nf * 16 * D + k0);
      bl[nf] = *reinterpret_cast<const bf8*>(bl_p + (size_t)nf * 16 * D + k0);
    }
#pragma unroll
    for (int nf = 0; nf < 4; ++nf)
      acc[nf] = __builtin_amdgcn_mfma_f32_16x16x32_bf16(ah, bh[nf], acc[nf], 0, 0, 0);
#pragma unroll
    for (int nf = 0; nf < 4; ++nf)
      acc[nf] = __builtin_amdgcn_mfma_f32_16x16x32_bf16(ah, bl[nf], acc[nf], 0, 0, 0);
#pragma unroll
    for (int nf = 0; nf < 4; ++nf)
      acc[nf] = __builtin_amdgcn_mfma_f32_16x16x32_bf16(al, bh[nf], acc[nf], 0, 0, 0);
  }
#pragma unroll
  for (int reg = 0; reg < 4; ++reg)
#pragma unroll
    for (int nf = 0; nf < 4; ++nf)
      Csh[w][((lane >> 4) << 2) + reg][nf * 16 + lr] = acc[nf][reg];
  __syncthreads();
  float s8 = S[8], s10 = S[10], s11 = S[11];
  int r = lr;
  int q = m0 + r;
  float aqv = aq[q];
#pragma unroll
  for (int cc = 0; cc < 2; ++cc) {
    int cl = ((lane >> 4) << 1) + cc;
    int c = blockIdx.y * 8 + cl;
    const float* t = &Csh[w][r][cl * 8];
    float e[6];
#pragma unroll
    for (int j = 0; j < 6; ++j) e[j] = t[j] - sv[c * 6 + j];
    float quad = 0.f;
#pragma unroll
    for (int i = 0; i < 6; ++i) {
      float a = 0.f;
#pragma unroll
      for (int j = 0; j < 6; ++j) a += Minv[c * 36 + i * 6 + j] * e[j];
      quad += e[i] * a;
    }
    float dist = (aqv - 2.f * t[6] + hb[c] - quad) * s8;
    out[(size_t)q * NC + c] = biasv[c] - s10 * log1pf(dist * s11);
  }
}

// per class: 7x7 Gram of fp32 UWp rows -> Minv, logdet, bias, sv, h.
__global__ __launch_bounds__(256) void k_msmall(const float* __restrict__ YYf,
                                                const float* __restrict__ S,
                                                float* __restrict__ Minv, float* __restrict__ biasv,
                                                float* __restrict__ hbuf, float* __restrict__ svec) {
  __shared__ float4 R4[7 * 128];
  __shared__ float Dsh[49];
  int c = blockIdx.x, tid = threadIdx.x;
  int lane = tid & 63, wave = tid >> 6;
  const float4* src = reinterpret_cast<const float4*>(YYf + (size_t)c * 8 * D);
  for (int idx = tid; idx < 7 * 128; idx += 256) R4[idx] = src[idx];
  __syncthreads();
  const float* R = reinterpret_cast<const float*>(R4);
  const int PI[28] = {0,0,0,0,0,0,0, 1,1,1,1,1,1, 2,2,2,2,2, 3,3,3,3, 4,4,4, 5,5, 6};
  const int PJ[28] = {0,1,2,3,4,5,6, 1,2,3,4,5,6, 2,3,4,5,6, 3,4,5,6, 4,5,6, 5,6, 6};
  for (int p = wave; p < 28; p += 4) {
    int i = PI[p], j = PJ[p];
    float part = 0.f;
#pragma unroll
    for (int it = 0; it < 8; ++it) {
      int d = lane + it * 64;
      part += R[i * D + d] * R[j * D + d];
    }
    part = wred(part);
    if (lane == 0) { Dsh[i * 7 + j] = part; Dsh[j * 7 + i] = part; }
  }
  __syncthreads();
  if (tid == 0) {
    float Mm[6][6], Rc[6][6], Rin[6][6];
    for (int i = 0; i < 6; ++i)
      for (int j = 0; j < 6; ++j) {
        Mm[i][j] = Dsh[i * 7 + j] + (i == j ? 1.f : 0.f);
        Rc[i][j] = 0.f; Rin[i][j] = 0.f;
      }
    float logdetM = 0.f;
    for (int i = 0; i < 6; ++i) {
      float s = Mm[i][i];
      for (int k = 0; k < i; ++k) s -= Rc[i][k] * Rc[i][k];
      float rii = sqrtf(s);
      Rc[i][i] = rii;
      logdetM += logf(rii);
      for (int r = i + 1; r < 6; ++r) {
        float s2 = Mm[r][i];
        for (int k = 0; k < i; ++k) s2 -= Rc[r][k] * Rc[i][k];
        Rc[r][i] = s2 / rii;
      }
    }
    logdetM *= 2.f;
    for (int j = 0; j < 6; ++j) {
      Rin[j][j] = 1.f / Rc[j][j];
      for (int i = j + 1; i < 6; ++i) {
        float s3 = 0.f;
        for (int k = j; k < i; ++k) s3 += Rc[i][k] * Rin[k][j];
        Rin[i][j] = -s3 / Rc[i][i];
      }
    }
    for (int i = 0; i < 6; ++i)
      for (int j = 0; j < 6; ++j) {
        float s4 = 0.f;
        for (int k = 0; k < 6; ++k) s4 += Rin[k][i] * Rin[k][j];
        Minv[c * 36 + i * 6 + j] = s4;
      }
    for (int j = 0; j < 6; ++j) svec[c * 6 + j] = Dsh[j * 7 + 6];
    hbuf[c] = Dsh[48];
    biasv[c] = S[3] - 0.5f * (S[9] + logdetM);
  }
}

extern "C" void kernel_launch(void* const* d_in, const int* in_sizes, int n_in,
                              void* d_out, int out_size, void* d_ws, size_t ws_size,
                              hipStream_t stream) {
  const float* Xs   = (const float*)d_in[0];
  const float* Xq   = (const float*)d_in[2];
  const float* m    = (const float*)d_in[3];
  const float* kap  = (const float*)d_in[4];
  const float* nu   = (const float*)d_in[5];
  const float* diag = (const float*)d_in[6];
  const float* low  = (const float*)d_in[7];
  float* ws = (float*)d_ws;

  float* S    = ws + OFF_S;
  u16*   ABh  = (u16*)(ws + OFF_ABH);
  u16*   ABl  = (u16*)(ws + OFF_ABL);
  u16*   Lh   = (u16*)(ws + OFF_LH);
  u16*   Ll   = (u16*)(ws + OFF_LL);
  u16*   Wh   = (u16*)(ws + OFF_WH);
  u16*   Wl   = (u16*)(ws + OFF_WL);
  u16*   YYh  = (u16*)(ws + OFF_YYH);
  u16*   YYl  = (u16*)(ws + OFF_YYL);
  float* YYf  = ws + OFF_YYF;
  float* aq   = ws + OFF_AQ;
  float* Minv = ws + OFF_MINV;
  float* bias = ws + OFF_BIAS;
  float* hb   = ws + OFF_H;
  float* sv   = ws + OFF_SV;

  hipLaunchKernelGGL(k_prep, dim3(1609), dim3(256), 0, stream,
                     diag, low, Xs, Xq, m, kap, nu, Lh, Ll, ABh, ABl, Wh, Wl, S, aq);
  hipLaunchKernelGGL(k_solve, dim3(16), dim3(256), 0, stream, Lh, Ll, Wh, Wl);
  // GEMM1: YY = [Ubp;Xq] @ W^T (2560x512x512 tri-clipped) + aq atomics
  hipLaunchKernelGGL(k_mf1, dim3(40, 8), dim3(256), 0, stream,
                     ABh, ABl, Wh, Wl, YYh, YYl, YYf, aq);
  hipLaunchKernelGGL(k_msmall, dim3(NC), dim3(256), 0, stream, YYf, S, Minv, bias, hb, sv);
  // GEMM2: out = epilogue(Y @ UWp^T) (2048x512x512)
  hipLaunchKernelGGL(k_mf2, dim3(32, 8), dim3(256), 0, stream,
                     YYh + (size_t)512 * D, YYl + (size_t)512 * D, YYh, YYl,
                     aq, sv, Minv, bias, hb, S, (float*)d_out);
}

// Round 10
// 79.996 us; speedup vs baseline: 2.4785x; 1.3285x over previous
//
#include <hip/hip_runtime.h>
#include <math.h>

#define D 512
#define NC 64
#define NQ 2048

typedef unsigned short u16;
typedef __attribute__((ext_vector_type(8))) short bf8;
typedef __attribute__((ext_vector_type(4))) float f4;

// ---- workspace float offsets ----
#define OFF_S    0
#define OFF_ABH  32                       // 2560x512 u16 (rows 0-511 Ubp, 512+ Xq) hi
#define OFF_ABL  (OFF_ABH + 655360)
#define OFF_LH   (OFF_ABL + 655360)       // 512x512 u16 L hi/lo
#define OFF_LL   (OFF_LH + 131072)
#define OFF_WH   (OFF_LL + 131072)        // 512x512 u16 W hi/lo
#define OFF_WL   (OFF_WH + 131072)
#define OFF_YYH  (OFF_WL + 131072)        // 2560x512 u16 YY hi; lo only rows>=512
#define OFF_YYL  (OFF_YYH + 655360)
#define OFF_AQ   (OFF_YYL + 655360)       // 2048 fp32
#define OFF_GRAM (OFF_AQ + NQ)            // 64*28 fp32 packed upper-tri 7x7 Grams
// total ~ 3.15M floats ~ 12.6 MB

#define GIX(i, j) ((i) * 7 - (i) * ((i) + 1) / 2 + (j))

__device__ inline float wred(float v) {
#pragma unroll
  for (int off = 32; off; off >>= 1) v += __shfl_down(v, off);
  return v;
}

// split fp32 into hi bf16 (truncated, so v-hi is exact) + lo bf16 (RN)
__device__ inline void split2(float v, u16& h, u16& l) {
  unsigned u = __float_as_uint(v);
  h = (u16)(u >> 16);
  float hf = __uint_as_float(u & 0xFFFF0000u);
  float r = v - hf;
  unsigned ru = __float_as_uint(r);
  l = (u16)((ru + 0x7FFFu + ((ru >> 16) & 1u)) >> 16);
}

#define MPAD 68
template <int N>
__device__ inline void lds_mm(float (*M)[MPAD], int ar, int ac, int br, int bc,
                              int cr, int cc, bool neg) {
  const int T = N / 16;
  int tx = (threadIdx.x & 15) * T, ty = (threadIdx.x >> 4) * T;
  float acc[T][T];
#pragma unroll
  for (int i = 0; i < T; ++i)
#pragma unroll
    for (int j = 0; j < T; ++j) acc[i][j] = 0.f;
#pragma unroll 8
  for (int k = 0; k < N; ++k) {
    float a[T], b[T];
#pragma unroll
    for (int i = 0; i < T; ++i) a[i] = M[ar + ty + i][ac + k];
#pragma unroll
    for (int j = 0; j < T; ++j) b[j] = M[br + k][bc + tx + j];
#pragma unroll
    for (int i = 0; i < T; ++i)
#pragma unroll
      for (int j = 0; j < T; ++j) acc[i][j] += a[i] * b[j];
  }
#pragma unroll
  for (int i = 0; i < T; ++i)
#pragma unroll
    for (int j = 0; j < T; ++j)
      M[cr + ty + i][cc + tx + j] = neg ? -acc[i][j] : acc[i][j];
}

// Fused prep (1609 blocks):
//   0..1023   : L -> Lh/Ll split; zero W upper (hi)
//   1024..1087: classprep -> ABh/ABl rows c*8..
//   1088      : scalars + aq/Gram zero
//   1089..1600: Xq -> ABh/ABl rows 512..
//   1601..1608: invert 64x64 diag block of L in LDS -> W diag (h/l)
__global__ __launch_bounds__(256) void k_prep(const float* __restrict__ diag,
                                              const float* __restrict__ low,
                                              const float* __restrict__ Xs,
                                              const float* __restrict__ Xq,
                                              const float* __restrict__ m,
                                              const float* __restrict__ kp,
                                              const float* __restrict__ nup,
                                              u16* __restrict__ Lh, u16* __restrict__ Ll,
                                              u16* __restrict__ ABh, u16* __restrict__ ABl,
                                              u16* __restrict__ Wh, u16* __restrict__ Wl,
                                              float* __restrict__ S, float* __restrict__ aq,
                                              float* __restrict__ Gram) {
  __shared__ float M[64][MPAD];
  int bid = blockIdx.x, tid = threadIdx.x;
  if (bid < 1024) {
    int t = bid * 256 + tid;
    int i = t >> 9, j = t & 511;
    float v = (i == j) ? fabsf(diag[i]) : (i > j ? low[t] : 0.f);
    u16 hh, ll; split2(v, hh, ll);
    Lh[t] = hh; Ll[t] = ll;
    if (i < j) Wh[t] = 0;
  } else if (bid < 1088) {
    int c = bid - 1024;
    float kappa = kp[0];
    float kn = fabsf(kappa) + 1e-6f + 5.0f;
    float xw = 5.0f / kn;
    float mw = fabsf(kappa + 1e-6f) / kn;
    float sw = sqrtf((fabsf(kappa) + 1e-6f) / kn);
    const float is5 = 0.44721359549995793f;
    for (int d = tid; d < D; d += 256) {
      float x[5];
#pragma unroll
      for (int s = 0; s < 5; ++s) x[s] = Xs[(size_t)(c * 5 + s) * D + d];
      float xm = (x[0] + x[1] + x[2] + x[3] + x[4]) * 0.2f;
      float mv = m[d];
      float rowv[8];
#pragma unroll
      for (int s = 0; s < 5; ++s) rowv[s] = x[s] * is5;
      rowv[5] = sw * (xm - mv);
      rowv[6] = mw * mv + xw * xm;
      rowv[7] = 0.f;
#pragma unroll
      for (int s = 0; s < 8; ++s) {
        size_t gi = (size_t)(c * 8 + s) * D + d;
        u16 hh, ll; split2(rowv[s], hh, ll);
        ABh[gi] = hh; ABl[gi] = ll;
      }
    }
  } else if (bid == 1088) {
    for (int i = tid; i < NQ; i += 256) aq[i] = 0.f;
    for (int i = tid; i < NC * 28; i += 256) Gram[i] = 0.f;
    if (tid >= 64) return;
    float part = 0.f;
    for (int i = tid; i < D; i += 64) part += logf(fabsf(diag[i]));
    part = wred(part);
    if (tid != 0) return;
    float lda = 2.f * part;
    float kappa = kp[0], nu = nup[0];
    float kn = fabsf(kappa) + 1e-6f + 5.0f;
    float sp = fmaxf(nu, (float)(D - 1) + 1e-6f) + 5.0f - (float)D + 2.0f;
    float bias_shared = lgammaf(0.5f * (sp + (float)D)) - lgammaf(0.5f * sp)
                      - 0.5f * (float)D * logf(sp);
    float scale = kn * sp / (kn + 1.0f);
    S[3] = bias_shared;
    S[8] = 1.f / scale;
    S[9] = (float)D * logf(scale) + lda;
    S[10] = 0.5f * (sp + (float)D);
    S[11] = 1.f / sp;
  } else if (bid < 1601) {
    int idx = bid - 1089;
    size_t base = (size_t)512 * D + (size_t)idx * 2048;
    for (int i = tid; i < 2048; i += 256) {
      float v = Xq[(size_t)idx * 2048 + i];
      u16 hh, ll; split2(v, hh, ll);
      ABh[base + i] = hh; ABl[base + i] = ll;
    }
  } else {
    // invert diag block (64x64) built directly from inputs
    int p = (bid - 1601) * 64;
    for (int idx = tid; idx < 64 * 64; idx += 256) {
      int r = idx >> 6, c = idx & 63;
      float v;
      if (r == c)      v = fabsf(diag[p + r]);
      else if (r > c)  v = low[(size_t)(p + r) * D + p + c];
      else             v = 0.f;
      M[r][c] = v;
    }
    __syncthreads();
    {
      float x[16];
      int q = tid >> 4, col = tid & 15;
      if (tid < 64) {
        int b = q << 4;
#pragma unroll
        for (int i = 0; i < 16; ++i) {
          float acc = 0.f;
#pragma unroll
          for (int k = 0; k < i; ++k) acc += M[b + i][b + k] * x[k];
          x[i] = (((i == col) ? 1.f : 0.f) - acc) / M[b + i][b + i];
        }
      }
      __syncthreads();
      if (tid < 64) {
        int b = q << 4;
#pragma unroll
        for (int i = 0; i < 16; ++i) M[b + i][b + col] = x[i];
      }
      __syncthreads();
    }
    for (int pp = 0; pp < 2; ++pp) {
      int r0 = 32 * pp;
      lds_mm<16>(M, r0 + 16, r0, r0, r0, r0, r0 + 16, false);
    }
    __syncthreads();
    for (int pp = 0; pp < 2; ++pp) {
      int r0 = 32 * pp;
      lds_mm<16>(M, r0 + 16, r0 + 16, r0, r0 + 16, r0 + 16, r0, true);
    }
    __syncthreads();
    lds_mm<32>(M, 32, 0, 0, 0, 0, 32, false);
    __syncthreads();
    lds_mm<32>(M, 32, 32, 0, 32, 32, 0, true);
    __syncthreads();
    for (int idx = tid; idx < 64 * 64; idx += 256) {
      int r = idx >> 6, c = idx & 63;
      float v = (c > r) ? 0.f : M[r][c];
      u16 hh, ll; split2(v, hh, ll);
      size_t gi = (size_t)(p + r) * D + p + c;
      Wh[gi] = hh; Wl[gi] = ll;
    }
  }
}

// One-kernel W = L^{-1} column-panel solve (MFMA split-bf16, 3-pass).
// Block J owns W cols [32J, 32J+32). Forward substitution over 64-row blocks.
__global__ __launch_bounds__(256) void k_solve(const u16* __restrict__ Lh,
                                               const u16* __restrict__ Ll,
                                               u16* __restrict__ Wh,
                                               u16* __restrict__ Wl) {
  __shared__ __align__(16) u16 XTh[32][520];
  __shared__ __align__(16) u16 XTl[32][520];
  __shared__ __align__(16) u16 STh[32][72];
  __shared__ __align__(16) u16 STl[32][72];
  int J = blockIdx.x;
  int i0 = J >> 1;
  int tid = threadIdx.x, w = tid >> 6, lane = tid & 63;
  int lr = lane & 15, kq = lane >> 4;
  for (int idx = tid; idx < 64 * 32; idx += 256) {
    int r = idx >> 5, c = idx & 31;
    size_t gi = (size_t)(64 * i0 + r) * D + 64 * i0 + (J & 1) * 32 + c;
    XTh[c][64 * i0 + r] = Wh[gi];
    XTl[c][64 * i0 + r] = Wl[gi];
  }
  __syncthreads();
  for (int i = i0 + 1; i < 8; ++i) {
    f4 acc[2];
    acc[0] = (f4){0.f, 0.f, 0.f, 0.f};
    acc[1] = (f4){0.f, 0.f, 0.f, 0.f};
    for (int k = i0; k < i; ++k) {
#pragma unroll
      for (int kk = 0; kk < 2; ++kk) {
        size_t ga = (size_t)(64 * i + w * 16 + lr) * D + 64 * k + kk * 32 + kq * 8;
        bf8 ah = *reinterpret_cast<const bf8*>(Lh + ga);
        bf8 al = *reinterpret_cast<const bf8*>(Ll + ga);
#pragma unroll
        for (int nf = 0; nf < 2; ++nf) {
          bf8 bh = *reinterpret_cast<const bf8*>(&XTh[nf * 16 + lr][64 * k + kk * 32 + kq * 8]);
          bf8 bl = *reinterpret_cast<const bf8*>(&XTl[nf * 16 + lr][64 * k + kk * 32 + kq * 8]);
          acc[nf] = __builtin_amdgcn_mfma_f32_16x16x32_bf16(ah, bh, acc[nf], 0, 0, 0);
          acc[nf] = __builtin_amdgcn_mfma_f32_16x16x32_bf16(ah, bl, acc[nf], 0, 0, 0);
          acc[nf] = __builtin_amdgcn_mfma_f32_16x16x32_bf16(al, bh, acc[nf], 0, 0, 0);
        }
      }
    }
#pragma unroll
    for (int nf = 0; nf < 2; ++nf)
#pragma unroll
      for (int reg = 0; reg < 4; ++reg) {
        float v = -acc[nf][reg];
        u16 hh, ll; split2(v, hh, ll);
        int c = nf * 16 + lr, r = w * 16 + kq * 4 + reg;
        STh[c][r] = hh; STl[c][r] = ll;
      }
    __syncthreads();
    f4 acc2[2];
    acc2[0] = (f4){0.f, 0.f, 0.f, 0.f};
    acc2[1] = (f4){0.f, 0.f, 0.f, 0.f};
#pragma unroll
    for (int kk = 0; kk < 2; ++kk) {
      size_t ga = (size_t)(64 * i + w * 16 + lr) * D + 64 * i + kk * 32 + kq * 8;
      bf8 ah = *reinterpret_cast<const bf8*>(Wh + ga);
      bf8 al = *reinterpret_cast<const bf8*>(Wl + ga);
#pragma unroll
      for (int nf = 0; nf < 2; ++nf) {
        bf8 bh = *reinterpret_cast<const bf8*>(&STh[nf * 16 + lr][kk * 32 + kq * 8]);
        bf8 bl = *reinterpret_cast<const bf8*>(&STl[nf * 16 + lr][kk * 32 + kq * 8]);
        acc2[nf] = __builtin_amdgcn_mfma_f32_16x16x32_bf16(ah, bh, acc2[nf], 0, 0, 0);
        acc2[nf] = __builtin_amdgcn_mfma_f32_16x16x32_bf16(ah, bl, acc2[nf], 0, 0, 0);
        acc2[nf] = __builtin_amdgcn_mfma_f32_16x16x32_bf16(al, bh, acc2[nf], 0, 0, 0);
      }
    }
#pragma unroll
    for (int nf = 0; nf < 2; ++nf)
#pragma unroll
      for (int reg = 0; reg < 4; ++reg) {
        float v = acc2[nf][reg];
        u16 hh, ll; split2(v, hh, ll);
        int r = w * 16 + kq * 4 + reg, c = nf * 16 + lr;
        size_t gi = (size_t)(64 * i + r) * D + 32 * J + c;
        Wh[gi] = hh;                     // off-diag Wl never consumed: skip
        XTh[c][64 * i + r] = hh; XTl[c][64 * i + r] = ll;
      }
    __syncthreads();
  }
}

// GEMM1 (MFMA split-bf16, 2-pass hh+lh): YY = [Ubp;Xq] @ W^T, tri-clipped.
// Fused: bf16 YYh (all rows) / YYl (Y rows only); aq (Y rows);
// 7x7 class Grams via LDS tile + atomics (UW rows, bx<8).
__global__ __launch_bounds__(256) void k_mf1(const u16* __restrict__ ABh, const u16* __restrict__ ABl,
                                             const u16* __restrict__ Wh,
                                             u16* __restrict__ YYh, u16* __restrict__ YYl,
                                             float* __restrict__ Gram, float* __restrict__ aq) {
  __shared__ float Csh[64][68];
  int tid = threadIdx.x, w = tid >> 6, lane = tid & 63;
  int m0 = blockIdx.x * 64 + w * 16;
  int bn = blockIdx.y * 64;
  int lr = lane & 15, kof = (lane >> 4) * 8;
  const u16* ah_p = ABh + (size_t)(m0 + lr) * D + kof;
  const u16* al_p = ABl + (size_t)(m0 + lr) * D + kof;
  const u16* bh_p = Wh + (size_t)(bn + lr) * D + kof;
  f4 acc[4];
#pragma unroll
  for (int nf = 0; nf < 4; ++nf) acc[nf] = (f4){0.f, 0.f, 0.f, 0.f};
  int Klim = bn + 64;
#pragma unroll 2
  for (int k0 = 0; k0 < Klim; k0 += 32) {
    bf8 ah = *reinterpret_cast<const bf8*>(ah_p + k0);
    bf8 al = *reinterpret_cast<const bf8*>(al_p + k0);
    bf8 bh[4];
#pragma unroll
    for (int nf = 0; nf < 4; ++nf)
      bh[nf] = *reinterpret_cast<const bf8*>(bh_p + (size_t)nf * 16 * D + k0);
#pragma unroll
    for (int nf = 0; nf < 4; ++nf)
      acc[nf] = __builtin_amdgcn_mfma_f32_16x16x32_bf16(ah, bh[nf], acc[nf], 0, 0, 0);
#pragma unroll
    for (int nf = 0; nf < 4; ++nf)
      acc[nf] = __builtin_amdgcn_mfma_f32_16x16x32_bf16(al, bh[nf], acc[nf], 0, 0, 0);
  }
  int rbase = m0 + ((lane >> 4) << 2);   // C layout: row=(lane>>4)*4+reg, col=lane&15
#pragma unroll
  for (int reg = 0; reg < 4; ++reg) {
    int row = rbase + reg;
    float sq = 0.f;
#pragma unroll
    for (int nf = 0; nf < 4; ++nf) {
      float v = acc[nf][reg];
      size_t gi = (size_t)row * D + bn + nf * 16 + lr;
      u16 hh, ll; split2(v, hh, ll);
      YYh[gi] = hh;
      if (row >= 512) YYl[gi] = ll;
      sq += v * v;
    }
    if (row >= 512) {
#pragma unroll
      for (int mk = 1; mk < 16; mk <<= 1) sq += __shfl_xor(sq, mk);
      if (lr == 0) atomicAdd(&aq[row - 512], sq);
    }
  }
  if (blockIdx.x < 8) {
    // partial 7x7 Grams for this block's 8 classes over its 64-col strip
#pragma unroll
    for (int reg = 0; reg < 4; ++reg)
#pragma unroll
      for (int nf = 0; nf < 4; ++nf)
        Csh[w * 16 + ((lane >> 4) << 2) + reg][nf * 16 + lr] = acc[nf][reg];
    __syncthreads();
    if (tid < 224) {
      const int PI[28] = {0,0,0,0,0,0,0, 1,1,1,1,1,1, 2,2,2,2,2, 3,3,3,3, 4,4,4, 5,5, 6};
      const int PJ[28] = {0,1,2,3,4,5,6, 1,2,3,4,5,6, 2,3,4,5,6, 3,4,5,6, 4,5,6, 5,6, 6};
      int cl = tid / 28, p = tid % 28;
      const float* ri = Csh[cl * 8 + PI[p]];
      const float* rj = Csh[cl * 8 + PJ[p]];
      float s = 0.f;
#pragma unroll
      for (int c4 = 0; c4 < 64; c4 += 4) {
        float4 a = *reinterpret_cast<const float4*>(&ri[c4]);
        float4 b = *reinterpret_cast<const float4*>(&rj[c4]);
        s += a.x * b.x + a.y * b.y + a.z * b.z + a.w * b.w;
      }
      atomicAdd(&Gram[(blockIdx.x * 8 + cl) * 28 + p], s);
    }
  }
}

// GEMM2 (MFMA split-bf16, 2-pass hh+lh) + per-block Cholesky prologue +
// fused MetaQDA epilogue via forward-substitution quad.
__global__ __launch_bounds__(256) void k_mf2(const u16* __restrict__ Yh, const u16* __restrict__ Yl,
                                             const u16* __restrict__ Bh,
                                             const float* __restrict__ aq,
                                             const float* __restrict__ Gram,
                                             const float* __restrict__ S,
                                             float* __restrict__ out) {
  __shared__ float Csh[4][16][68];
  __shared__ float PRo[8][15], PRd[8][6], Psv[8][6], Pb[8], Ph[8];
  int tid = threadIdx.x, w = tid >> 6, lane = tid & 63;
  int m0 = blockIdx.x * 64 + w * 16;
  int bn = blockIdx.y * 64;
  int lr = lane & 15, kof = (lane >> 4) * 8;
  const u16* ah_p = Yh + (size_t)(m0 + lr) * D + kof;
  const u16* al_p = Yl + (size_t)(m0 + lr) * D + kof;
  const u16* bh_p = Bh + (size_t)(bn + lr) * D + kof;
  f4 acc[4];
#pragma unroll
  for (int nf = 0; nf < 4; ++nf) acc[nf] = (f4){0.f, 0.f, 0.f, 0.f};
#pragma unroll 2
  for (int k0 = 0; k0 < D; k0 += 32) {
    bf8 ah = *reinterpret_cast<const bf8*>(ah_p + k0);
    bf8 al = *reinterpret_cast<const bf8*>(al_p + k0);
    bf8 bh[4];
#pragma unroll
    for (int nf = 0; nf < 4; ++nf)
      bh[nf] = *reinterpret_cast<const bf8*>(bh_p + (size_t)nf * 16 * D + k0);
#pragma unroll
    for (int nf = 0; nf < 4; ++nf)
      acc[nf] = __builtin_amdgcn_mfma_f32_16x16x32_bf16(ah, bh[nf], acc[nf], 0, 0, 0);
#pragma unroll
    for (int nf = 0; nf < 4; ++nf)
      acc[nf] = __builtin_amdgcn_mfma_f32_16x16x32_bf16(al, bh[nf], acc[nf], 0, 0, 0);
  }
#pragma unroll
  for (int reg = 0; reg < 4; ++reg)
#pragma unroll
    for (int nf = 0; nf < 4; ++nf)
      Csh[w][((lane >> 4) << 2) + reg][nf * 16 + lr] = acc[nf][reg];
  if (tid < 8) {
    // prologue: Cholesky of M = I + G6x6 for class c; publish R, sv, h, bias
    int c = blockIdx.y * 8 + tid;
    float Gv[28];
#pragma unroll
    for (int p = 0; p < 28; ++p) Gv[p] = Gram[c * 28 + p];
    float R[6][6];
    float logdetM = 0.f;
#pragma unroll
    for (int i = 0; i < 6; ++i) {
      float s = Gv[GIX(i, i)] + 1.f;
#pragma unroll
      for (int k = 0; k < i; ++k) s -= R[i][k] * R[i][k];
      float rii = sqrtf(s);
      R[i][i] = rii;
      logdetM += logf(rii);
      float inv = 1.f / rii;
      PRd[tid][i] = inv;
#pragma unroll
      for (int r = i + 1; r < 6; ++r) {
        float s2 = Gv[GIX(i, r)];
#pragma unroll
        for (int k = 0; k < i; ++k) s2 -= R[r][k] * R[i][k];
        R[r][i] = s2 * inv;
      }
    }
#pragma unroll
    for (int i = 1; i < 6; ++i)
#pragma unroll
      for (int k = 0; k < i; ++k)
        PRo[tid][i * (i - 1) / 2 + k] = R[i][k];
#pragma unroll
    for (int j = 0; j < 6; ++j) Psv[tid][j] = Gv[GIX(j, 6)];
    Ph[tid] = Gv[27];
    Pb[tid] = S[3] - 0.5f * (S[9] + 2.f * logdetM);
  }
  __syncthreads();
  float s8 = S[8], s10 = S[10], s11 = S[11];
  int r = lr;
  int q = m0 + r;
  float aqv = aq[q];
#pragma unroll
  for (int cc = 0; cc < 2; ++cc) {
    int cl = ((lane >> 4) << 1) + cc;
    const float* t = &Csh[w][r][cl * 8];
    float e[6];
#pragma unroll
    for (int j = 0; j < 6; ++j) e[j] = t[j] - Psv[cl][j];
    const float* o = PRo[cl];
    const float* dg = PRd[cl];
    float z0 = e[0] * dg[0];
    float z1 = (e[1] - o[0] * z0) * dg[1];
    float z2 = (e[2] - o[1] * z0 - o[2] * z1) * dg[2];
    float z3 = (e[3] - o[3] * z0 - o[4] * z1 - o[5] * z2) * dg[3];
    float z4 = (e[4] - o[6] * z0 - o[7] * z1 - o[8] * z2 - o[9] * z3) * dg[4];
    float z5 = (e[5] - o[10] * z0 - o[11] * z1 - o[12] * z2 - o[13] * z3 - o[14] * z4) * dg[5];
    float quad = z0 * z0 + z1 * z1 + z2 * z2 + z3 * z3 + z4 * z4 + z5 * z5;
    float dist = (aqv - 2.f * t[6] + Ph[cl] - quad) * s8;
    out[(size_t)q * NC + blockIdx.y * 8 + cl] = Pb[cl] - s10 * log1pf(dist * s11);
  }
}

extern "C" void kernel_launch(void* const* d_in, const int* in_sizes, int n_in,
                              void* d_out, int out_size, void* d_ws, size_t ws_size,
                              hipStream_t stream) {
  const float* Xs   = (const float*)d_in[0];
  const float* Xq   = (const float*)d_in[2];
  const float* m    = (const float*)d_in[3];
  const float* kap  = (const float*)d_in[4];
  const float* nu   = (const float*)d_in[5];
  const float* diag = (const float*)d_in[6];
  const float* low  = (const float*)d_in[7];
  float* ws = (float*)d_ws;

  float* S    = ws + OFF_S;
  u16*   ABh  = (u16*)(ws + OFF_ABH);
  u16*   ABl  = (u16*)(ws + OFF_ABL);
  u16*   Lh   = (u16*)(ws + OFF_LH);
  u16*   Ll   = (u16*)(ws + OFF_LL);
  u16*   Wh   = (u16*)(ws + OFF_WH);
  u16*   Wl   = (u16*)(ws + OFF_WL);
  u16*   YYh  = (u16*)(ws + OFF_YYH);
  u16*   YYl  = (u16*)(ws + OFF_YYL);
  float* aq   = ws + OFF_AQ;
  float* Gram = ws + OFF_GRAM;

  hipLaunchKernelGGL(k_prep, dim3(1609), dim3(256), 0, stream,
                     diag, low, Xs, Xq, m, kap, nu, Lh, Ll, ABh, ABl, Wh, Wl, S, aq, Gram);
  hipLaunchKernelGGL(k_solve, dim3(16), dim3(256), 0, stream, Lh, Ll, Wh, Wl);
  // GEMM1: YY = [Ubp;Xq] @ W^T (tri-clipped) + aq + class Grams
  hipLaunchKernelGGL(k_mf1, dim3(40, 8), dim3(256), 0, stream,
                     ABh, ABl, Wh, YYh, YYl, Gram, aq);
  // GEMM2: out = epilogue(Y @ UWp^T) with per-block Cholesky prologue
  hipLaunchKernelGGL(k_mf2, dim3(32, 8), dim3(256), 0, stream,
                     YYh + (size_t)512 * D, YYl + (size_t)512 * D, YYh,
                     aq, Gram, S, (float*)d_out);
}